// Round 1
// baseline (13.754 us; speedup 1.0000x reference)
//
#include <hip/hip_runtime.h>

// Rotation: U = kron(I_27, M, I_81) applied to complex (6561, 512) state.
// M = expm(-0.5i*theta*Sx(0,1)) = [[c,-is,0],[-is,c,0],[0,0,1]], phi = theta/2.
// Layout: n = (outer*3 + mid)*81 + inner; x[n,b] at n*512+b (row-major).
// Output: [real(N*B), imag(N*B)] stacked.

constexpr int B4     = 128;              // 512 floats / 4 per float4
constexpr int STRIDE = 81;               // D^(L-1-INDEX) = 3^4
constexpr int OUTER  = 27;               // D^INDEX = 3^3
constexpr int NB4    = 6561 * B4;        // float4 count of one (N,B) plane
constexpr int TOTAL  = OUTER * STRIDE * B4;  // 279936 threads

__global__ __launch_bounds__(256) void rot_kernel(
    const float4* __restrict__ xr, const float4* __restrict__ xi,
    const float* __restrict__ angle,
    float4* __restrict__ outr, float4* __restrict__ outi)
{
    int idx = blockIdx.x * blockDim.x + threadIdx.x;
    if (idx >= TOTAL) return;

    float phi = 0.5f * angle[0];
    float c = cosf(phi);
    float s = sinf(phi);

    int b4    = idx % B4;
    int t     = idx / B4;
    int inner = t % STRIDE;
    int outer = t / STRIDE;

    int r0 = (outer * 3) * STRIDE + inner;   // row for mid=0
    int o0 = r0 * B4 + b4;
    int o1 = o0 + STRIDE * B4;               // mid=1
    int o2 = o1 + STRIDE * B4;               // mid=2

    float4 x0r = xr[o0], x0i = xi[o0];
    float4 x1r = xr[o1], x1i = xi[o1];
    float4 x2r = xr[o2], x2i = xi[o2];

    float4 y0r, y0i, y1r, y1i;
#define APPLY(f)                                   \
    y0r.f =  c * x0r.f + s * x1i.f;                \
    y0i.f =  c * x0i.f - s * x1r.f;                \
    y1r.f =  s * x0i.f + c * x1r.f;                \
    y1i.f = -s * x0r.f + c * x1i.f;
    APPLY(x) APPLY(y) APPLY(z) APPLY(w)
#undef APPLY

    outr[o0] = y0r;  outi[o0] = y0i;
    outr[o1] = y1r;  outi[o1] = y1i;
    outr[o2] = x2r;  outi[o2] = x2i;
}

extern "C" void kernel_launch(void* const* d_in, const int* in_sizes, int n_in,
                              void* d_out, int out_size, void* d_ws, size_t ws_size,
                              hipStream_t stream) {
    const float4* xr    = (const float4*)d_in[0];
    const float4* xi    = (const float4*)d_in[1];
    const float*  angle = (const float*)d_in[2];

    float4* outr = (float4*)d_out;
    float4* outi = outr + NB4;

    int blocks = (TOTAL + 255) / 256;
    rot_kernel<<<blocks, 256, 0, stream>>>(xr, xi, angle, outr, outi);
}

// Round 2
// 13.643 us; speedup vs baseline: 1.0082x; 1.0082x over previous
//
#include <hip/hip_runtime.h>

// Rotation: U = kron(I_27, M, I_81) applied to complex (6561, 512) state.
// M = expm(-0.5i*theta*Sx(0,1)) = [[c,-is,0],[-is,c,0],[0,0,1]], phi = theta/2.
// out0 = (c*x0r + s*x1i) + i(c*x0i - s*x1r)
// out1 = (s*x0i + c*x1r) + i(-s*x0r + c*x1i)
// out2 = x2 (copy)
//
// Work split for occupancy (TLP over ILP): rotation threads own a (row0,row1)
// pair (4 loads/4 stores); copy threads own a row2 chunk (2 loads/2 stores).
// 559872 threads = 8748 waves (~34/CU) vs 4374 in the fused version.
// Boundary 279936 = 4374*64 is wave-aligned -> role branch is wave-uniform.

constexpr int B4     = 128;              // 512 floats / 4 per float4
constexpr int STRIDE = 81;               // D^(L-1-INDEX) = 3^4
constexpr int OUTER  = 27;               // D^INDEX = 3^3
constexpr int NB4    = 6561 * B4;        // float4 count of one (N,B) plane
constexpr int TOTAL_PAIR = OUTER * STRIDE * B4;   // 279936
constexpr int TOTAL      = 2 * TOTAL_PAIR;        // 559872 = 2187 * 256 exactly

__global__ __launch_bounds__(256) void rot_kernel(
    const float4* __restrict__ xr, const float4* __restrict__ xi,
    const float* __restrict__ angle,
    float4* __restrict__ outr, float4* __restrict__ outi)
{
    int idx = blockIdx.x * blockDim.x + threadIdx.x;

    const bool copy_role = idx >= TOTAL_PAIR;      // wave-uniform
    int w = copy_role ? idx - TOTAL_PAIR : idx;

    int b4    = w % B4;                            // pow2 -> and
    int t     = w / B4;                            // pow2 -> shift
    int inner = t % STRIDE;                        // magic-mul
    int outer = t / STRIDE;

    int o0 = ((outer * 3) * STRIDE + inner) * B4 + b4;   // mid=0 chunk

    if (copy_role) {
        int o2 = o0 + 2 * STRIDE * B4;             // mid=2
        float4 vr = xr[o2];
        float4 vi = xi[o2];
        outr[o2] = vr;
        outi[o2] = vi;
    } else {
        int o1 = o0 + STRIDE * B4;                 // mid=1

        float4 x0r = xr[o0], x0i = xi[o0];
        float4 x1r = xr[o1], x1i = xi[o1];

        float phi = 0.5f * angle[0];
        float c = cosf(phi);
        float s = sinf(phi);

        float4 y0r, y0i, y1r, y1i;
#define APPLY(f)                                   \
        y0r.f =  c * x0r.f + s * x1i.f;            \
        y0i.f =  c * x0i.f - s * x1r.f;            \
        y1r.f =  s * x0i.f + c * x1r.f;            \
        y1i.f = -s * x0r.f + c * x1i.f;
        APPLY(x) APPLY(y) APPLY(z) APPLY(w)
#undef APPLY

        outr[o0] = y0r;  outi[o0] = y0i;
        outr[o1] = y1r;  outi[o1] = y1i;
    }
}

extern "C" void kernel_launch(void* const* d_in, const int* in_sizes, int n_in,
                              void* d_out, int out_size, void* d_ws, size_t ws_size,
                              hipStream_t stream) {
    const float4* xr    = (const float4*)d_in[0];
    const float4* xi    = (const float4*)d_in[1];
    const float*  angle = (const float*)d_in[2];

    float4* outr = (float4*)d_out;
    float4* outi = outr + NB4;

    rot_kernel<<<TOTAL / 256, 256, 0, stream>>>(xr, xi, angle, outr, outi);
}